// Round 11
// baseline (101.362 us; speedup 1.0000x reference)
//
#include <hip/hip_runtime.h>
#include <hip/hip_bf16.h>

// Problem constants (from reference)
#define BATCH   8
#define MROWS   2048      // C*P per batch
#define MTOT    16384     // BATCH*MROWS
#define DIM_Z   512
#define DIM_G   1024
#define EDIM    128
#define EPS     1e-6f
#define BK      128       // fat K-step

typedef unsigned short u16;
typedef unsigned int   u32;
typedef __attribute__((ext_vector_type(8))) short bf16x8;
typedef __attribute__((ext_vector_type(4))) float f32x4;
typedef __attribute__((ext_vector_type(4))) float fvec4;   // ext-vector for NT builtins
typedef __attribute__((ext_vector_type(4))) u32   u32x4;

// f32 -> bf16 round-to-nearest-even (bit trick; inputs are finite)
__device__ __forceinline__ u16 f2b(float f) {
    u32 x = __float_as_uint(f);
    u32 r = x + 0x7fffu + ((x >> 16) & 1u);
    return (u16)(r >> 16);
}

// async global->LDS, 16B per lane, dest = wave-uniform base + lane*16
#define GLD16(gsrc, ldst) __builtin_amdgcn_global_load_lds( \
    (const __attribute__((address_space(1))) unsigned int*)(gsrc), \
    (__attribute__((address_space(3))) unsigned int*)(ldst), 16, 0, 0)

// ---- kernel 1: u = a_emb @ Wu^T, v = a_emb @ Wv^T (coalesced); zero rsum/tacc ----
__global__ void uv_kernel(const float* __restrict__ emb, const int* __restrict__ idx,
                          const float* __restrict__ Wu, const float* __restrict__ Wv,
                          float* __restrict__ u, float* __restrict__ v,
                          float* __restrict__ zbuf) {   // zbuf = rsum(16384) + tacc(16384)
    __shared__ float a[EDIM];
    int b = blockIdx.y;
    int t = threadIdx.x;
    if (blockIdx.x == 0)   // zero 2*MTOT/BATCH = 4096 floats per b
        for (int i = t; i < 4096; i += 256) zbuf[(size_t)b * 4096 + i] = 0.f;
    if (t < EDIM) a[t] = emb[(size_t)idx[b] * EDIM + t];
    __syncthreads();
    int tx = t & 31, ty = t >> 5;
    int oBase = blockIdx.x * 256;
    for (int o0 = 0; o0 < 256; o0 += 8) {
        int o = oBase + o0 + ty;
        const float* wrow = (o < DIM_G) ? (Wu + (size_t)o * EDIM)
                                        : (Wv + (size_t)(o - DIM_G) * EDIM);
        float s = 0.f;
#pragma unroll
        for (int q = 0; q < 4; ++q) s += a[q * 32 + tx] * wrow[q * 32 + tx];
        s += __shfl_xor(s, 1, 64);
        s += __shfl_xor(s, 2, 64);
        s += __shfl_xor(s, 4, 64);
        s += __shfl_xor(s, 8, 64);
        s += __shfl_xor(s, 16, 64);
        if (tx == 0) {
            if (o < DIM_G) u[b * DIM_G + o] = s;
            else           v[b * DIM_Z + (o - DIM_G)] = s;
        }
    }
}

// ---- kernel 2: W_base f32 -> bf16 (Wb16 [G][D]) + transposed (WbT16 [D][G]) ----
// Tiny (1 MB in, 2 MB out), one-time. Replaces the old 48 MB wpack.
__global__ void wpack2(const float* __restrict__ Wb,
                       u16* __restrict__ W16, u16* __restrict__ WT16) {
    __shared__ u16 tile[32][33];
    int h = blockIdx.x;                 // 512 blocks: 16 d-tiles x 32 g-tiles
    int d0 = (h & 15) * 32, g0 = (h >> 4) * 32;
    int tx = threadIdx.x, ty = threadIdx.y;
#pragma unroll
    for (int j = 0; j < 4; ++j) {
        int g = g0 + ty + j * 8;
        u16 w = f2b(Wb[(size_t)g * DIM_Z + d0 + tx]);
        W16[(size_t)g * DIM_Z + d0 + tx] = w;
        tile[ty + j * 8][tx] = w;
    }
    __syncthreads();
#pragma unroll
    for (int j = 0; j < 4; ++j)
        WT16[(size_t)(d0 + ty + j * 8) * DIM_G + g0 + tx] = tile[tx][ty + j * 8];
}

// ---- kernel 3: cast qz -> bf16 AND s[m] = qz_row . v[b]  (one qz pass) ----
// One wave per row (64 lanes x 8 f32 = 512 = full row). XCD-aligned: b = h&7.
__global__ void cast_s(const float* __restrict__ qz, const float* __restrict__ v,
                       u16* __restrict__ qzb, float* __restrict__ svec) {
    int h = blockIdx.x;                  // 1024 blocks; 16 rows each
    int b = h & 7, i = h >> 3;           // i in [0,128)
    int lane = threadIdx.x & 63, w = threadIdx.x >> 6;
    float vf[8];
    const float* vb = v + b * DIM_Z + lane * 8;
#pragma unroll
    for (int e = 0; e < 8; ++e) vf[e] = vb[e];
#pragma unroll
    for (int p = 0; p < 4; ++p) {
        int row = b * MROWS + i * 16 + p * 4 + w;
        const float* src = qz + (size_t)row * DIM_Z + lane * 8;
        fvec4 f0 = __builtin_nontemporal_load((const fvec4*)src);
        fvec4 f1 = __builtin_nontemporal_load((const fvec4*)src + 1);
        float s = f0.x * vf[0] + f0.y * vf[1] + f0.z * vf[2] + f0.w * vf[3]
                + f1.x * vf[4] + f1.y * vf[5] + f1.z * vf[6] + f1.w * vf[7];
        union { u16 us[8]; u32x4 q; } o;
        o.us[0] = f2b(f0.x); o.us[1] = f2b(f0.y); o.us[2] = f2b(f0.z); o.us[3] = f2b(f0.w);
        o.us[4] = f2b(f1.x); o.us[5] = f2b(f1.y); o.us[6] = f2b(f1.z); o.us[7] = f2b(f1.w);
        *(u32x4*)(qzb + (size_t)row * DIM_Z + lane * 8) = o.q;
#pragma unroll
        for (int d = 1; d < 64; d <<= 1) s += __shfl_xor(s, d, 64);
        if (lane == 0) svec[row] = s;
    }
}

// ---------------- GEMM: C[m,n] = sum_k A[m,k] * Bt[n,k] + rank-1 epilogue -------
// SINGLE GEMM over M=16384 (all batches), B = shared 1MB W_base panel (L2-hot
// everywhere). BK=128 (4 or 8 iterations total): half the barrier-drain count.
// Staging: global_load_lds w16, linear LDS [128][128], source chunk pre-swizzled
// cw = c' ^ (row&15), reads apply same XOR (2-way bank conflicts = free, m136).
// XCD decode: xcd = h&7 owns contiguous m-range (A panels + own qg slice hot).
// EPI=0: raw = acc + s[m]*u[b,g]; val = relu(raw); bf16 store (qg);
//        rsum[m] += sum(val), tacc[m] += sum(val*u[b,g])  (shfl + atomics).
// EPI=1: out = (acc + tacc[m]*v[b,d]) / max(rsum[m],eps), f32 NT-store.
template <int EPI, int NTLOG>
__global__ __launch_bounds__(256, 2)
void gemm_bt(const u16* __restrict__ A, const u16* __restrict__ Bt,
             void* __restrict__ Call,
             const float* __restrict__ svec, const float* __restrict__ uvvec,
             float* __restrict__ rsum, float* __restrict__ tacc,
             int N, int K) {
    __shared__ u16 As[128 * BK];   // 32 KB
    __shared__ u16 Bs[128 * BK];   // 32 KB

    int h = blockIdx.x;
    int xcd = h & 7, idx = h >> 3;
    int tile = xcd * (16 << NTLOG) + idx;        // per-XCD contiguous m-range
    int mT = tile >> NTLOG;
    int nBase = (tile & ((1 << NTLOG) - 1)) * 128;
    int mBase = mT * 128;
    int b = mBase >> 11;                          // batch of this m-tile

    int tid  = threadIdx.x;
    int lane = tid & 63, wid = tid >> 6;
    int wm = wid >> 1, wn = wid & 1;
    int lr = lane & 15, lg = lane >> 4;

    f32x4 acc[4][4] = {};

    // staging: slot s = r*256+tid; row = r*16 + (tid>>4); c' = tid&15;
    // physical chunk cw = c' ^ (row&15) = c' ^ (tid>>4 & 15).
    int sRow = tid >> 4;                          // 0..15
    int cw   = (tid & 15) ^ sRow;
    const u16* aSrc = A  + (size_t)(mBase + sRow) * K + cw * 8;
    const u16* bSrc = Bt + (size_t)(nBase + sRow) * K + cw * 8;

    for (int kt = 0; kt < K; kt += BK) {
        __syncthreads();   // previous tile's reads done before overwrite
#pragma unroll
        for (int r = 0; r < 8; ++r) {
            GLD16(aSrc + (size_t)r * 16 * K + kt, &As[(r * 256 + wid * 64) * 8]);
            GLD16(bSrc + (size_t)r * 16 * K + kt, &Bs[(r * 256 + wid * 64) * 8]);
        }
        __syncthreads();   // tile landed
#pragma unroll
        for (int ks = 0; ks < 4; ++ks) {
            bf16x8 af[4], bfr[4];
#pragma unroll
            for (int mi = 0; mi < 4; ++mi) {
                int row = wm * 64 + mi * 16 + lr;
                int cq  = (ks * 4 + lg) ^ (row & 15);
                af[mi] = *(const bf16x8*)&As[row * BK + cq * 8];
            }
#pragma unroll
            for (int ni = 0; ni < 4; ++ni) {
                int row = wn * 64 + ni * 16 + lr;
                int cq  = (ks * 4 + lg) ^ (row & 15);
                bfr[ni] = *(const bf16x8*)&Bs[row * BK + cq * 8];
            }
#pragma unroll
            for (int mi = 0; mi < 4; ++mi)
#pragma unroll
                for (int ni = 0; ni < 4; ++ni)
                    acc[mi][ni] = __builtin_amdgcn_mfma_f32_16x16x32_bf16(
                        af[mi], bfr[ni], acc[mi][ni], 0, 0, 0);
        }
    }

    int mw = mBase + wm * 64, nw = nBase + wn * 64;
    if (EPI == 0) {
        u16* C = (u16*)Call;
        float ucol[4];
#pragma unroll
        for (int ni = 0; ni < 4; ++ni)
            ucol[ni] = uvvec[b * DIM_G + nw + ni * 16 + lr];   // u[b, g]
#pragma unroll
        for (int mi = 0; mi < 4; ++mi)
#pragma unroll
            for (int r = 0; r < 4; ++r) {
                int m = mw + mi * 16 + lg * 4 + r;
                float sm = svec[m];
                float s1 = 0.f, s2 = 0.f;
                float vals[4];
#pragma unroll
                for (int ni = 0; ni < 4; ++ni) {
                    float raw = acc[mi][ni][r] + sm * ucol[ni];
                    float val = fmaxf(raw, 0.f);
                    vals[ni] = val;
                    s1 += val;
                    s2 += val * ucol[ni];
                }
#pragma unroll
                for (int ni = 0; ni < 4; ++ni)
                    C[(size_t)m * N + nw + ni * 16 + lr] = f2b(vals[ni]);
                s1 += __shfl_xor(s1, 1, 64); s2 += __shfl_xor(s2, 1, 64);
                s1 += __shfl_xor(s1, 2, 64); s2 += __shfl_xor(s2, 2, 64);
                s1 += __shfl_xor(s1, 4, 64); s2 += __shfl_xor(s2, 4, 64);
                s1 += __shfl_xor(s1, 8, 64); s2 += __shfl_xor(s2, 8, 64);
                if (lr == 0) {
                    atomicAdd(&rsum[m], s1);
                    atomicAdd(&tacc[m], s2);
                }
            }
    } else {
        float* C = (float*)Call;
        float vcol[4];
#pragma unroll
        for (int ni = 0; ni < 4; ++ni)
            vcol[ni] = uvvec[b * DIM_Z + nw + ni * 16 + lr];   // v[b, d]
#pragma unroll
        for (int mi = 0; mi < 4; ++mi)
#pragma unroll
            for (int r = 0; r < 4; ++r) {
                int m = mw + mi * 16 + lg * 4 + r;
                float inv = 1.f / fmaxf(rsum[m], EPS);
                float t = tacc[m];
#pragma unroll
                for (int ni = 0; ni < 4; ++ni)
                    __builtin_nontemporal_store((acc[mi][ni][r] + t * vcol[ni]) * inv,
                        &C[(size_t)m * N + nw + ni * 16 + lr]);
            }
    }
}

extern "C" void kernel_launch(void* const* d_in, const int* in_sizes, int n_in,
                              void* d_out, int out_size, void* d_ws, size_t ws_size,
                              hipStream_t stream) {
    const float* qz    = (const float*)d_in[0];
    const int*   attr  = (const int*)d_in[1];
    const float* Wbase = (const float*)d_in[2];
    const float* emb   = (const float*)d_in[3];
    const float* Wu    = (const float*)d_in[4];
    const float* Wv    = (const float*)d_in[5];
    float* out = (float*)d_out;

    // workspace carve-up (all 256B aligned)
    char* ws = (char*)d_ws;
    size_t off = 0;
    auto alloc = [&](size_t bytes) -> void* {
        void* p = ws + off;
        off = (off + bytes + 255) & ~(size_t)255;
        return p;
    };
    float* u    = (float*)alloc((size_t)BATCH * DIM_G * 4);
    float* v    = (float*)alloc((size_t)BATCH * DIM_Z * 4);
    float* zbuf = (float*)alloc((size_t)2 * MTOT * 4);      // rsum | tacc
    float* svec = (float*)alloc((size_t)MTOT * 4);
    u16*   qzb  = (u16*)  alloc((size_t)MTOT * DIM_Z * 2);
    u16*   W16  = (u16*)  alloc((size_t)DIM_G * DIM_Z * 2);
    u16*   WT16 = (u16*)  alloc((size_t)DIM_G * DIM_Z * 2);
    u16*   qg   = (u16*)  alloc((size_t)MTOT * DIM_G * 2);
    if (off > ws_size) return;  // fail loudly (zero output) rather than corrupt
    float* rsum = zbuf;
    float* tacc = zbuf + MTOT;

    uv_kernel<<<dim3(6, BATCH), dim3(256), 0, stream>>>(emb, attr, Wu, Wv, u, v, zbuf);

    wpack2<<<dim3(512), dim3(32, 8), 0, stream>>>(Wbase, W16, WT16);

    // cast + s = qz.v  (single qz pass, XCD-aligned)
    cast_s<<<dim3(1024), dim3(256), 0, stream>>>(qz, v, qzb, svec);

    // GEMM1: qg = relu(qzb @ W16^T + s u^T); rsum/tacc epilogue.
    // 128 mT x 8 nT = 1024 blocks (NTLOG=3)
    gemm_bt<0, 3><<<dim3(1024), dim3(256), 0, stream>>>(
        qzb, W16, qg, svec, u, rsum, tacc, DIM_G, DIM_Z);

    // GEMM2: out = (qg @ WT16^T + tacc v^T) / max(rsum,eps).
    // 128 mT x 4 nT = 512 blocks (NTLOG=2)
    gemm_bt<1, 2><<<dim3(512), dim3(256), 0, stream>>>(
        qg, WT16, out, svec, v, rsum, tacc, DIM_Z, DIM_G);
}

// Round 12
// 98.607 us; speedup vs baseline: 1.0279x; 1.0279x over previous
//
#include <hip/hip_runtime.h>
#include <hip/hip_bf16.h>

// Problem constants (from reference)
#define BATCH   8
#define MROWS   2048      // C*P per batch
#define MTOT    16384     // BATCH*MROWS
#define DIM_Z   512
#define DIM_G   1024
#define EDIM    128
#define EPS     1e-6f
#define BK      64        // K-step

typedef unsigned short u16;
typedef unsigned int   u32;
typedef __attribute__((ext_vector_type(8))) short bf16x8;
typedef __attribute__((ext_vector_type(4))) float f32x4;
typedef __attribute__((ext_vector_type(4))) float fvec4;   // ext-vector for NT builtins
typedef __attribute__((ext_vector_type(4))) u32   u32x4;

// f32 -> bf16 round-to-nearest-even (bit trick; inputs are finite)
__device__ __forceinline__ u16 f2b(float f) {
    u32 x = __float_as_uint(f);
    u32 r = x + 0x7fffu + ((x >> 16) & 1u);
    return (u16)(r >> 16);
}

// async global->LDS, 16B per lane, dest = wave-uniform base + lane*16
#define GLD16(gsrc, ldst) __builtin_amdgcn_global_load_lds( \
    (const __attribute__((address_space(1))) unsigned int*)(gsrc), \
    (__attribute__((address_space(3))) unsigned int*)(ldst), 16, 0, 0)

// ---- kernel 1: u = a_emb @ Wu^T, v = a_emb @ Wv^T (coalesced); zero rsum/tacc ----
__global__ void uv_kernel(const float* __restrict__ emb, const int* __restrict__ idx,
                          const float* __restrict__ Wu, const float* __restrict__ Wv,
                          float* __restrict__ u, float* __restrict__ v,
                          float* __restrict__ zbuf) {   // zbuf = rsum(16384) + tacc(16384)
    __shared__ float a[EDIM];
    int b = blockIdx.y;
    int t = threadIdx.x;
    if (blockIdx.x == 0)   // zero 2*MTOT/BATCH = 4096 floats per b
        for (int i = t; i < 4096; i += 256) zbuf[(size_t)b * 4096 + i] = 0.f;
    if (t < EDIM) a[t] = emb[(size_t)idx[b] * EDIM + t];
    __syncthreads();
    int tx = t & 31, ty = t >> 5;
    int oBase = blockIdx.x * 256;
    for (int o0 = 0; o0 < 256; o0 += 8) {
        int o = oBase + o0 + ty;
        const float* wrow = (o < DIM_G) ? (Wu + (size_t)o * EDIM)
                                        : (Wv + (size_t)(o - DIM_G) * EDIM);
        float s = 0.f;
#pragma unroll
        for (int q = 0; q < 4; ++q) s += a[q * 32 + tx] * wrow[q * 32 + tx];
        s += __shfl_xor(s, 1, 64);
        s += __shfl_xor(s, 2, 64);
        s += __shfl_xor(s, 4, 64);
        s += __shfl_xor(s, 8, 64);
        s += __shfl_xor(s, 16, 64);
        if (tx == 0) {
            if (o < DIM_G) u[b * DIM_G + o] = s;
            else           v[b * DIM_Z + (o - DIM_G)] = s;
        }
    }
}

// ---- kernel 2: W_base f32 -> bf16 (W16 [G][D]) + transposed (WT16 [D][G]) ----
__global__ void wpack2(const float* __restrict__ Wb,
                       u16* __restrict__ W16, u16* __restrict__ WT16) {
    __shared__ u16 tile[32][33];
    int h = blockIdx.x;                 // 512 blocks: 16 d-tiles x 32 g-tiles
    int d0 = (h & 15) * 32, g0 = (h >> 4) * 32;
    int tx = threadIdx.x, ty = threadIdx.y;
#pragma unroll
    for (int j = 0; j < 4; ++j) {
        int g = g0 + ty + j * 8;
        u16 w = f2b(Wb[(size_t)g * DIM_Z + d0 + tx]);
        W16[(size_t)g * DIM_Z + d0 + tx] = w;
        tile[ty + j * 8][tx] = w;
    }
    __syncthreads();
#pragma unroll
    for (int j = 0; j < 4; ++j)
        WT16[(size_t)(d0 + ty + j * 8) * DIM_G + g0 + tx] = tile[tx][ty + j * 8];
}

// ---- kernel 3: cast qz -> bf16 AND s[m] = qz_row . v[b]  (one qz pass) ----
// One wave per row (64 lanes x 8 f32 = 512 = full row). XCD-aligned: b = h&7.
__global__ void cast_s(const float* __restrict__ qz, const float* __restrict__ v,
                       u16* __restrict__ qzb, float* __restrict__ svec) {
    int h = blockIdx.x;                  // 1024 blocks; 16 rows each
    int b = h & 7, i = h >> 3;           // i in [0,128)
    int lane = threadIdx.x & 63, w = threadIdx.x >> 6;
    float vf[8];
    const float* vb = v + b * DIM_Z + lane * 8;
#pragma unroll
    for (int e = 0; e < 8; ++e) vf[e] = vb[e];
#pragma unroll
    for (int p = 0; p < 4; ++p) {
        int row = b * MROWS + i * 16 + p * 4 + w;
        const float* src = qz + (size_t)row * DIM_Z + lane * 8;
        fvec4 f0 = __builtin_nontemporal_load((const fvec4*)src);
        fvec4 f1 = __builtin_nontemporal_load((const fvec4*)src + 1);
        float s = f0.x * vf[0] + f0.y * vf[1] + f0.z * vf[2] + f0.w * vf[3]
                + f1.x * vf[4] + f1.y * vf[5] + f1.z * vf[6] + f1.w * vf[7];
        union { u16 us[8]; u32x4 q; } o;
        o.us[0] = f2b(f0.x); o.us[1] = f2b(f0.y); o.us[2] = f2b(f0.z); o.us[3] = f2b(f0.w);
        o.us[4] = f2b(f1.x); o.us[5] = f2b(f1.y); o.us[6] = f2b(f1.z); o.us[7] = f2b(f1.w);
        *(u32x4*)(qzb + (size_t)row * DIM_Z + lane * 8) = o.q;
#pragma unroll
        for (int d = 1; d < 64; d <<= 1) s += __shfl_xor(s, d, 64);
        if (lane == 0) svec[row] = s;
    }
}

// ---------------- GEMM: C[m,n] = sum_k A[m,k] * Bt[n,k] + rank-1 epilogue -------
// FAT-WAVE restructure (this round's lever — LDS-read-BW bound diagnosis):
// block 128m x 256n, BK=64; 4 waves (2M x 2N), wave tile 64x128 (acc 4x8).
// Per kstep a wave reads 4 A + 8 B frags (12 KB) for 32 MFMA -> 43.7 FLOP per
// LDS byte vs 32.8 before (1.33x fewer LDS reads); block LDS = 48 KB/kstep.
// Staging via global_load_lds w16, linear LDS, source chunk pre-swizzled
// cw = c' ^ (row&7), reads apply the same XOR (rule #21; 0 conflicts measured).
// XCD decode: xcd = h&7 owns a contiguous m-range (same range in GEMM1+GEMM2,
// so qg stays in that XCD's L2); within XCD n-fastest for A-panel sharing.
// EPI=0: raw = acc + s[m]*u[b,g]; val = relu(raw); bf16 store (qg);
//        rsum[m] += sum(val), tacc[m] += sum(val*u[b,g])  (shfl + atomics).
// EPI=1: out = (acc + tacc[m]*v[b,d]) / max(rsum[m],eps), f32 NT-store.
template <int EPI, int NTLOG>
__global__ __launch_bounds__(256, 2)
void gemm_bt(const u16* __restrict__ A, const u16* __restrict__ Bt,
             void* __restrict__ Call,
             const float* __restrict__ svec, const float* __restrict__ uvvec,
             float* __restrict__ rsum, float* __restrict__ tacc,
             int N, int K) {
    __shared__ u16 As[128 * BK];   // 16 KB
    __shared__ u16 Bs[256 * BK];   // 32 KB

    int h = blockIdx.x;
    int xcd = h & 7, idx = h >> 3;
    int tile = xcd * (16 << NTLOG) + idx;        // per-XCD contiguous m-range
    int mT = tile >> NTLOG;
    int nBase = (tile & ((1 << NTLOG) - 1)) * 256;
    int mBase = mT * 128;
    int b = mBase >> 11;                          // batch of this m-tile

    int tid  = threadIdx.x;
    int lane = tid & 63, wid = tid >> 6;
    int wm = wid >> 1, wn = wid & 1;              // 2M x 2N fat waves
    int lr = lane & 15, lg = lane >> 4;

    f32x4 acc[4][8] = {};

    // staging: slot s = r*256+tid; row = r*32 + (tid>>3); c' = tid&7;
    // physical chunk cw = c' ^ (row&7) = c' ^ ((tid>>3)&7)  (r*32 % 8 == 0).
    int sRow = tid >> 3;                          // 0..31
    int cw   = (tid & 7) ^ (sRow & 7);
    const u16* aSrc = A  + (size_t)(mBase + sRow) * K + cw * 8;
    const u16* bSrc = Bt + (size_t)(nBase + sRow) * K + cw * 8;

    for (int kt = 0; kt < K; kt += BK) {
        __syncthreads();   // previous tile's reads done before overwrite
#pragma unroll
        for (int r = 0; r < 4; ++r)               // A: 128 rows
            GLD16(aSrc + (size_t)r * 32 * K + kt, &As[(r * 256 + wid * 64) * 8]);
#pragma unroll
        for (int r = 0; r < 8; ++r)               // B: 256 rows
            GLD16(bSrc + (size_t)r * 32 * K + kt, &Bs[(r * 256 + wid * 64) * 8]);
        __syncthreads();   // tile landed
#pragma unroll
        for (int ks = 0; ks < 2; ++ks) {
            bf16x8 af[4], bfr[8];
#pragma unroll
            for (int mi = 0; mi < 4; ++mi) {
                int row = wm * 64 + mi * 16 + lr;
                int cq  = (ks * 4 + lg) ^ (row & 7);
                af[mi] = *(const bf16x8*)&As[row * BK + cq * 8];
            }
#pragma unroll
            for (int ni = 0; ni < 8; ++ni) {
                int row = wn * 128 + ni * 16 + lr;
                int cq  = (ks * 4 + lg) ^ (row & 7);
                bfr[ni] = *(const bf16x8*)&Bs[row * BK + cq * 8];
            }
            __builtin_amdgcn_s_setprio(1);
#pragma unroll
            for (int mi = 0; mi < 4; ++mi)
#pragma unroll
                for (int ni = 0; ni < 8; ++ni)
                    acc[mi][ni] = __builtin_amdgcn_mfma_f32_16x16x32_bf16(
                        af[mi], bfr[ni], acc[mi][ni], 0, 0, 0);
            __builtin_amdgcn_s_setprio(0);
        }
    }

    int mw = mBase + wm * 64, nw = nBase + wn * 128;
    if (EPI == 0) {
        u16* C = (u16*)Call;
        float ucol[8];
#pragma unroll
        for (int ni = 0; ni < 8; ++ni)
            ucol[ni] = uvvec[b * DIM_G + nw + ni * 16 + lr];   // u[b, g]
#pragma unroll
        for (int mi = 0; mi < 4; ++mi)
#pragma unroll
            for (int r = 0; r < 4; ++r) {
                int m = mw + mi * 16 + lg * 4 + r;
                float sm = svec[m];
                float s1 = 0.f, s2 = 0.f;
                float vals[8];
#pragma unroll
                for (int ni = 0; ni < 8; ++ni) {
                    float raw = acc[mi][ni][r] + sm * ucol[ni];
                    float val = fmaxf(raw, 0.f);
                    vals[ni] = val;
                    s1 += val;
                    s2 += val * ucol[ni];
                }
#pragma unroll
                for (int ni = 0; ni < 8; ++ni)
                    C[(size_t)m * N + nw + ni * 16 + lr] = f2b(vals[ni]);
                s1 += __shfl_xor(s1, 1, 64); s2 += __shfl_xor(s2, 1, 64);
                s1 += __shfl_xor(s1, 2, 64); s2 += __shfl_xor(s2, 2, 64);
                s1 += __shfl_xor(s1, 4, 64); s2 += __shfl_xor(s2, 4, 64);
                s1 += __shfl_xor(s1, 8, 64); s2 += __shfl_xor(s2, 8, 64);
                if (lr == 0) {
                    atomicAdd(&rsum[m], s1);
                    atomicAdd(&tacc[m], s2);
                }
            }
    } else {
        float* C = (float*)Call;
        float vcol[8];
#pragma unroll
        for (int ni = 0; ni < 8; ++ni)
            vcol[ni] = uvvec[b * DIM_Z + nw + ni * 16 + lr];   // v[b, d]
#pragma unroll
        for (int mi = 0; mi < 4; ++mi)
#pragma unroll
            for (int r = 0; r < 4; ++r) {
                int m = mw + mi * 16 + lg * 4 + r;
                float inv = 1.f / fmaxf(rsum[m], EPS);
                float t = tacc[m];
#pragma unroll
                for (int ni = 0; ni < 8; ++ni)
                    __builtin_nontemporal_store((acc[mi][ni][r] + t * vcol[ni]) * inv,
                        &C[(size_t)m * N + nw + ni * 16 + lr]);
            }
    }
}

extern "C" void kernel_launch(void* const* d_in, const int* in_sizes, int n_in,
                              void* d_out, int out_size, void* d_ws, size_t ws_size,
                              hipStream_t stream) {
    const float* qz    = (const float*)d_in[0];
    const int*   attr  = (const int*)d_in[1];
    const float* Wbase = (const float*)d_in[2];
    const float* emb   = (const float*)d_in[3];
    const float* Wu    = (const float*)d_in[4];
    const float* Wv    = (const float*)d_in[5];
    float* out = (float*)d_out;

    // workspace carve-up (all 256B aligned)
    char* ws = (char*)d_ws;
    size_t off = 0;
    auto alloc = [&](size_t bytes) -> void* {
        void* p = ws + off;
        off = (off + bytes + 255) & ~(size_t)255;
        return p;
    };
    float* u    = (float*)alloc((size_t)BATCH * DIM_G * 4);
    float* v    = (float*)alloc((size_t)BATCH * DIM_Z * 4);
    float* zbuf = (float*)alloc((size_t)2 * MTOT * 4);      // rsum | tacc
    float* svec = (float*)alloc((size_t)MTOT * 4);
    u16*   qzb  = (u16*)  alloc((size_t)MTOT * DIM_Z * 2);
    u16*   W16  = (u16*)  alloc((size_t)DIM_G * DIM_Z * 2);
    u16*   WT16 = (u16*)  alloc((size_t)DIM_G * DIM_Z * 2);
    u16*   qg   = (u16*)  alloc((size_t)MTOT * DIM_G * 2);
    if (off > ws_size) return;  // fail loudly (zero output) rather than corrupt
    float* rsum = zbuf;
    float* tacc = zbuf + MTOT;

    uv_kernel<<<dim3(6, BATCH), dim3(256), 0, stream>>>(emb, attr, Wu, Wv, u, v, zbuf);

    wpack2<<<dim3(512), dim3(32, 8), 0, stream>>>(Wbase, W16, WT16);

    // cast + s = qz.v  (single qz pass, XCD-aligned)
    cast_s<<<dim3(1024), dim3(256), 0, stream>>>(qz, v, qzb, svec);

    // GEMM1: qg = relu(qzb @ W16^T + s u^T); rsum/tacc epilogue.
    // 128 mT x 4 nT = 512 blocks (NTLOG=2)
    gemm_bt<0, 2><<<dim3(512), dim3(256), 0, stream>>>(
        qzb, W16, qg, svec, u, rsum, tacc, DIM_G, DIM_Z);

    // GEMM2: out = (qg @ WT16^T + tacc v^T) / max(rsum,eps).
    // 128 mT x 2 nT = 256 blocks (NTLOG=1)
    gemm_bt<1, 1><<<dim3(256), dim3(256), 0, stream>>>(
        qg, WT16, out, svec, v, rsum, tacc, DIM_Z, DIM_G);
}

// Round 13
// 92.868 us; speedup vs baseline: 1.0915x; 1.0618x over previous
//
#include <hip/hip_runtime.h>
#include <hip/hip_bf16.h>

// Problem constants (from reference)
#define BATCH   8
#define MROWS   2048      // C*P per batch
#define MTOT    16384     // BATCH*MROWS
#define DIM_Z   512
#define DIM_G   1024
#define EDIM    128
#define EPS     1e-6f
#define BK      64        // K-step

typedef unsigned short u16;
typedef unsigned int   u32;
typedef __attribute__((ext_vector_type(8))) short bf16x8;
typedef __attribute__((ext_vector_type(4))) float f32x4;

// f32 -> bf16 round-to-nearest-even (bit trick; inputs are finite)
__device__ __forceinline__ u16 f2b(float f) {
    u32 x = __float_as_uint(f);
    u32 r = x + 0x7fffu + ((x >> 16) & 1u);
    return (u16)(r >> 16);
}

// async global->LDS, 16B per lane, dest = wave-uniform base + lane*16
#define GLD16(gsrc, ldst) __builtin_amdgcn_global_load_lds( \
    (const __attribute__((address_space(1))) unsigned int*)(gsrc), \
    (__attribute__((address_space(3))) unsigned int*)(ldst), 16, 0, 0)

// ---- kernel 1: u = a_emb @ Wu^T, v = a_emb @ Wv^T (+v16 bf16); zero rsum/tacc ----
__global__ void uv_kernel(const float* __restrict__ emb, const int* __restrict__ idx,
                          const float* __restrict__ Wu, const float* __restrict__ Wv,
                          float* __restrict__ u, float* __restrict__ v,
                          u16* __restrict__ v16, float* __restrict__ zbuf) {
    __shared__ float a[EDIM];
    int b = blockIdx.y;
    int t = threadIdx.x;
    if (blockIdx.x == 0)   // zero rsum|tacc slice for batch b (before GEMM1)
        for (int i = t; i < 4096; i += 256) zbuf[(size_t)b * 4096 + i] = 0.f;
    if (t < EDIM) a[t] = emb[(size_t)idx[b] * EDIM + t];
    __syncthreads();
    int tx = t & 31, ty = t >> 5;
    int oBase = blockIdx.x * 256;
    for (int o0 = 0; o0 < 256; o0 += 8) {
        int o = oBase + o0 + ty;
        const float* wrow = (o < DIM_G) ? (Wu + (size_t)o * EDIM)
                                        : (Wv + (size_t)(o - DIM_G) * EDIM);
        float s = 0.f;
#pragma unroll
        for (int q = 0; q < 4; ++q) s += a[q * 32 + tx] * wrow[q * 32 + tx];
        s += __shfl_xor(s, 1, 64);
        s += __shfl_xor(s, 2, 64);
        s += __shfl_xor(s, 4, 64);
        s += __shfl_xor(s, 8, 64);
        s += __shfl_xor(s, 16, 64);
        if (tx == 0) {
            if (o < DIM_G) u[b * DIM_G + o] = s;
            else {
                v[b * DIM_Z + (o - DIM_G)] = s;
                v16[b * DIM_Z + (o - DIM_G)] = f2b(s);
            }
        }
    }
}

// ---- kernel 2: W_base f32 -> bf16 (W16 [G][D]) + transposed (WT16 [D][G]) ----
__global__ void wpack2(const float* __restrict__ Wb,
                       u16* __restrict__ W16, u16* __restrict__ WT16) {
    __shared__ u16 tile[32][33];
    int h = blockIdx.x;                 // 512 blocks: 16 d-tiles x 32 g-tiles
    int d0 = (h & 15) * 32, g0 = (h >> 4) * 32;
    int tx = threadIdx.x, ty = threadIdx.y;
#pragma unroll
    for (int j = 0; j < 4; ++j) {
        int g = g0 + ty + j * 8;
        u16 w = f2b(Wb[(size_t)g * DIM_Z + d0 + tx]);
        W16[(size_t)g * DIM_Z + d0 + tx] = w;
        tile[ty + j * 8][tx] = w;
    }
    __syncthreads();
#pragma unroll
    for (int j = 0; j < 4; ++j)
        WT16[(size_t)(d0 + ty + j * 8) * DIM_G + g0 + tx] = tile[tx][ty + j * 8];
}

// ---------------- GEMM1: qg = relu(qz @ W16^T + (qz.v) u^T) ----------------
// A = qz f32 DIRECT (fused cast: reg-stage f32, cvt, swizzled ds_write — the
// r4-verified path). s[m] = qz.v computed IN-LOOP via one extra MFMA with a
// B-fragment that is v16 on column n=0 (lanes lr==0) and zero elsewhere; the
// K-loop spans the full K=512 so s is complete at the epilogue.
// 128x128 tile, 4 waves (2x2), BK=64. B staged via global_load_lds (linear
// dest, source chunk pre-swizzled cw = c'^(row&7); reads same XOR — rule #21).
// XCD decode: xcd = h&7 owns a contiguous batch-pure m-range; n-fastest within.
// Epilogue: raw = acc + s*u[g]; val = relu; bf16 qg store;
//           rsum[m] += sum(val), tacc[m] += sum(val*u[g])  (shfl + atomics).
__global__ __launch_bounds__(256, 3)
void gemm1(const float* __restrict__ qz, const u16* __restrict__ W16,
           const u16* __restrict__ v16, const float* __restrict__ u,
           u16* __restrict__ qg, float* __restrict__ rsum, float* __restrict__ tacc) {
    const int N = DIM_G, K = DIM_Z;
    __shared__ u16 As[128 * BK];   // 16 KB
    __shared__ u16 Bs[128 * BK];   // 16 KB

    int h = blockIdx.x;
    int xcd = h & 7, idx = h >> 3;
    int tile = xcd * 128 + idx;              // 16 mT x 8 nT per XCD
    int mBase = (tile >> 3) * 128;
    int nBase = (tile & 7) * 128;
    int b = mBase >> 11;

    int tid  = threadIdx.x;
    int lane = tid & 63, wid = tid >> 6;
    int wm = wid >> 1, wn = wid & 1;
    int lr = lane & 15, lg = lane >> 4;

    f32x4 acc[4][4] = {};
    f32x4 acc_s[4] = {};

    int sRow = tid >> 3;                      // 0..31
    int sC   = tid & 7;
    int cw   = sC ^ (sRow & 7);
    const float* aSrc = qz  + (size_t)(mBase + sRow) * K + sC * 8;  // straight read
    const u16*   bSrc = W16 + (size_t)(nBase + sRow) * K + cw * 8;  // pre-swizzled
    const u16*   v16b = v16 + b * DIM_Z;

    for (int kt = 0; kt < K; kt += BK) {
        float4 alo[4], ahi[4];
#pragma unroll
        for (int r = 0; r < 4; ++r) {         // issue-early: no LDS hazard
            const float* g = aSrc + (size_t)r * 32 * K + kt;
            alo[r] = *(const float4*)g;
            ahi[r] = *(const float4*)(g + 4);
        }
        bf16x8 vf0 = {}, vf1 = {};
        if (lr == 0) {                        // v-column fragments (k matches af)
            vf0 = *(const bf16x8*)(v16b + kt + lg * 8);
            vf1 = *(const bf16x8*)(v16b + kt + 32 + lg * 8);
        }
        __syncthreads();   // previous tile's reads done before overwrite
#pragma unroll
        for (int r = 0; r < 4; ++r)
            GLD16(bSrc + (size_t)r * 32 * K + kt, &Bs[(r * 256 + wid * 64) * 8]);
#pragma unroll
        for (int r = 0; r < 4; ++r) {         // cvt + swizzled ds_write
            union { u16 us[8]; uint4 q; } o;
            o.us[0] = f2b(alo[r].x); o.us[1] = f2b(alo[r].y);
            o.us[2] = f2b(alo[r].z); o.us[3] = f2b(alo[r].w);
            o.us[4] = f2b(ahi[r].x); o.us[5] = f2b(ahi[r].y);
            o.us[6] = f2b(ahi[r].z); o.us[7] = f2b(ahi[r].w);
            *(uint4*)&As[(r * 32 + sRow) * BK + cw * 8] = o.q;
        }
        __syncthreads();   // tile landed
#pragma unroll
        for (int ks = 0; ks < 2; ++ks) {
            bf16x8 af[4], bfr[4];
#pragma unroll
            for (int mi = 0; mi < 4; ++mi) {
                int row = wm * 64 + mi * 16 + lr;
                int cq  = (ks * 4 + lg) ^ (row & 7);
                af[mi] = *(const bf16x8*)&As[row * BK + cq * 8];
            }
#pragma unroll
            for (int ni = 0; ni < 4; ++ni) {
                int row = wn * 64 + ni * 16 + lr;
                int cq  = (ks * 4 + lg) ^ (row & 7);
                bfr[ni] = *(const bf16x8*)&Bs[row * BK + cq * 8];
            }
            __builtin_amdgcn_s_setprio(1);
#pragma unroll
            for (int mi = 0; mi < 4; ++mi) {
#pragma unroll
                for (int ni = 0; ni < 4; ++ni)
                    acc[mi][ni] = __builtin_amdgcn_mfma_f32_16x16x32_bf16(
                        af[mi], bfr[ni], acc[mi][ni], 0, 0, 0);
                acc_s[mi] = __builtin_amdgcn_mfma_f32_16x16x32_bf16(
                    af[mi], ks ? vf1 : vf0, acc_s[mi], 0, 0, 0);
            }
            __builtin_amdgcn_s_setprio(0);
        }
    }

    int mw = mBase + wm * 64, nw = nBase + wn * 64;
    float ucol[4];
#pragma unroll
    for (int ni = 0; ni < 4; ++ni)
        ucol[ni] = u[b * DIM_G + nw + ni * 16 + lr];
#pragma unroll
    for (int mi = 0; mi < 4; ++mi)
#pragma unroll
        for (int r = 0; r < 4; ++r) {
            int m = mw + mi * 16 + lg * 4 + r;
            float sm = __shfl(acc_s[mi][r], lane & 48, 64);  // bcast from lr==0
            float s1 = 0.f, s2 = 0.f;
            float vals[4];
#pragma unroll
            for (int ni = 0; ni < 4; ++ni) {
                float val = fmaxf(acc[mi][ni][r] + sm * ucol[ni], 0.f);
                vals[ni] = val;
                s1 += val;
                s2 += val * ucol[ni];
            }
#pragma unroll
            for (int ni = 0; ni < 4; ++ni)
                qg[(size_t)m * N + nw + ni * 16 + lr] = f2b(vals[ni]);
            s1 += __shfl_xor(s1, 1, 64); s2 += __shfl_xor(s2, 1, 64);
            s1 += __shfl_xor(s1, 2, 64); s2 += __shfl_xor(s2, 2, 64);
            s1 += __shfl_xor(s1, 4, 64); s2 += __shfl_xor(s2, 4, 64);
            s1 += __shfl_xor(s1, 8, 64); s2 += __shfl_xor(s2, 8, 64);
            if (lr == 0) {
                atomicAdd(&rsum[m], s1);
                atomicAdd(&tacc[m], s2);
            }
        }
}

// ---------------- GEMM2: out = (qg @ WT16^T + tacc v^T) / max(rsum,eps) -------
// r4-verified 128x128 / 4-wave structure, both operands via global_load_lds.
// Same per-XCD m-range as GEMM1 (qg L2-hot). NT store (out never re-read).
__global__ __launch_bounds__(256, 4)
void gemm2(const u16* __restrict__ qg, const u16* __restrict__ WT16,
           const float* __restrict__ v, float* __restrict__ out,
           const float* __restrict__ rsum, const float* __restrict__ tacc) {
    const int N = DIM_Z, K = DIM_G;
    __shared__ u16 As[128 * BK];   // 16 KB
    __shared__ u16 Bs[128 * BK];   // 16 KB

    int h = blockIdx.x;
    int xcd = h & 7, idx = h >> 3;
    int tile = xcd * 64 + idx;               // 16 mT x 4 nT per XCD
    int mBase = (tile >> 2) * 128;
    int nBase = (tile & 3) * 128;
    int b = mBase >> 11;

    int tid  = threadIdx.x;
    int lane = tid & 63, wid = tid >> 6;
    int wm = wid >> 1, wn = wid & 1;
    int lr = lane & 15, lg = lane >> 4;

    f32x4 acc[4][4] = {};

    int sRow = tid >> 3;
    int cw   = (tid & 7) ^ (sRow & 7);
    const u16* aSrc = qg   + (size_t)(mBase + sRow) * K + cw * 8;
    const u16* bSrc = WT16 + (size_t)(nBase + sRow) * K + cw * 8;

    for (int kt = 0; kt < K; kt += BK) {
        __syncthreads();
#pragma unroll
        for (int r = 0; r < 4; ++r) {
            GLD16(aSrc + (size_t)r * 32 * K + kt, &As[(r * 256 + wid * 64) * 8]);
            GLD16(bSrc + (size_t)r * 32 * K + kt, &Bs[(r * 256 + wid * 64) * 8]);
        }
        __syncthreads();
#pragma unroll
        for (int ks = 0; ks < 2; ++ks) {
            bf16x8 af[4], bfr[4];
#pragma unroll
            for (int mi = 0; mi < 4; ++mi) {
                int row = wm * 64 + mi * 16 + lr;
                int cq  = (ks * 4 + lg) ^ (row & 7);
                af[mi] = *(const bf16x8*)&As[row * BK + cq * 8];
            }
#pragma unroll
            for (int ni = 0; ni < 4; ++ni) {
                int row = wn * 64 + ni * 16 + lr;
                int cq  = (ks * 4 + lg) ^ (row & 7);
                bfr[ni] = *(const bf16x8*)&Bs[row * BK + cq * 8];
            }
            __builtin_amdgcn_s_setprio(1);
#pragma unroll
            for (int mi = 0; mi < 4; ++mi)
#pragma unroll
                for (int ni = 0; ni < 4; ++ni)
                    acc[mi][ni] = __builtin_amdgcn_mfma_f32_16x16x32_bf16(
                        af[mi], bfr[ni], acc[mi][ni], 0, 0, 0);
            __builtin_amdgcn_s_setprio(0);
        }
    }

    int mw = mBase + wm * 64, nw = nBase + wn * 64;
    float vcol[4];
#pragma unroll
    for (int ni = 0; ni < 4; ++ni)
        vcol[ni] = v[b * DIM_Z + nw + ni * 16 + lr];
#pragma unroll
    for (int mi = 0; mi < 4; ++mi)
#pragma unroll
        for (int r = 0; r < 4; ++r) {
            int m = mw + mi * 16 + lg * 4 + r;
            float inv = 1.f / fmaxf(rsum[m], EPS);
            float t = tacc[m];
#pragma unroll
            for (int ni = 0; ni < 4; ++ni)
                __builtin_nontemporal_store((acc[mi][ni][r] + t * vcol[ni]) * inv,
                    &out[(size_t)m * N + nw + ni * 16 + lr]);
        }
}

extern "C" void kernel_launch(void* const* d_in, const int* in_sizes, int n_in,
                              void* d_out, int out_size, void* d_ws, size_t ws_size,
                              hipStream_t stream) {
    const float* qz    = (const float*)d_in[0];
    const int*   attr  = (const int*)d_in[1];
    const float* Wbase = (const float*)d_in[2];
    const float* emb   = (const float*)d_in[3];
    const float* Wu    = (const float*)d_in[4];
    const float* Wv    = (const float*)d_in[5];
    float* out = (float*)d_out;

    // workspace carve-up (all 256B aligned)
    char* ws = (char*)d_ws;
    size_t off = 0;
    auto alloc = [&](size_t bytes) -> void* {
        void* p = ws + off;
        off = (off + bytes + 255) & ~(size_t)255;
        return p;
    };
    float* u    = (float*)alloc((size_t)BATCH * DIM_G * 4);
    float* v    = (float*)alloc((size_t)BATCH * DIM_Z * 4);
    u16*   v16  = (u16*)  alloc((size_t)BATCH * DIM_Z * 2);
    float* zbuf = (float*)alloc((size_t)2 * MTOT * 4);      // rsum | tacc
    u16*   W16  = (u16*)  alloc((size_t)DIM_G * DIM_Z * 2);
    u16*   WT16 = (u16*)  alloc((size_t)DIM_G * DIM_Z * 2);
    u16*   qg   = (u16*)  alloc((size_t)MTOT * DIM_G * 2);
    if (off > ws_size) return;  // fail loudly (zero output) rather than corrupt
    float* rsum = zbuf;
    float* tacc = zbuf + MTOT;

    uv_kernel<<<dim3(6, BATCH), dim3(256), 0, stream>>>(emb, attr, Wu, Wv, u, v, v16, zbuf);

    wpack2<<<dim3(512), dim3(32, 8), 0, stream>>>(Wbase, W16, WT16);

    // GEMM1: 16 mT x 8 nT x 8 xcd = 1024 blocks (fused cast + s-MFMA)
    gemm1<<<dim3(1024), dim3(256), 0, stream>>>(qz, W16, v16, u, qg, rsum, tacc);

    // GEMM2: 16 mT x 4 nT x 8 xcd = 512 blocks
    gemm2<<<dim3(512), dim3(256), 0, stream>>>(qg, WT16, v, out, rsum, tacc);
}

// Round 14
// 84.924 us; speedup vs baseline: 1.1936x; 1.0935x over previous
//
#include <hip/hip_runtime.h>
#include <hip/hip_bf16.h>

// Problem constants (from reference)
#define BATCH   8
#define MROWS   2048      // C*P per batch
#define MTOT    16384     // BATCH*MROWS
#define DIM_Z   512
#define DIM_G   1024
#define EDIM    128
#define EPS     1e-6f
#define BK      64        // K-step

typedef unsigned short u16;
typedef unsigned int   u32;
typedef __attribute__((ext_vector_type(8))) short bf16x8;
typedef __attribute__((ext_vector_type(4))) float f32x4;

// f32 -> bf16 round-to-nearest-even (bit trick; inputs are finite)
__device__ __forceinline__ u16 f2b(float f) {
    u32 x = __float_as_uint(f);
    u32 r = x + 0x7fffu + ((x >> 16) & 1u);
    return (u16)(r >> 16);
}

// async global->LDS, 16B per lane, dest = wave-uniform base + lane*16
#define GLD16(gsrc, ldst) __builtin_amdgcn_global_load_lds( \
    (const __attribute__((address_space(1))) unsigned int*)(gsrc), \
    (__attribute__((address_space(3))) unsigned int*)(ldst), 16, 0, 0)

// ---- kernel 1: u = a_emb @ Wu^T, v = a_emb @ Wv^T (coalesced); zero rsum ----
__global__ void uv_kernel(const float* __restrict__ emb, const int* __restrict__ idx,
                          const float* __restrict__ Wu, const float* __restrict__ Wv,
                          float* __restrict__ u, float* __restrict__ v,
                          float* __restrict__ rsum) {
    __shared__ float a[EDIM];
    int b = blockIdx.y;
    int t = threadIdx.x;
    if (blockIdx.x == 0)   // zero rsum slice for batch b (runs before GEMM1)
        for (int i = t; i < MROWS; i += 256) rsum[(size_t)b * MROWS + i] = 0.f;
    if (t < EDIM) a[t] = emb[(size_t)idx[b] * EDIM + t];
    __syncthreads();
    int tx = t & 31, ty = t >> 5;
    int oBase = blockIdx.x * 256;
    for (int o0 = 0; o0 < 256; o0 += 8) {
        int o = oBase + o0 + ty;
        const float* wrow = (o < DIM_G) ? (Wu + (size_t)o * EDIM)
                                        : (Wv + (size_t)(o - DIM_G) * EDIM);
        float s = 0.f;
#pragma unroll
        for (int q = 0; q < 4; ++q) s += a[q * 32 + tx] * wrow[q * 32 + tx];
        s += __shfl_xor(s, 1, 64);
        s += __shfl_xor(s, 2, 64);
        s += __shfl_xor(s, 4, 64);
        s += __shfl_xor(s, 8, 64);
        s += __shfl_xor(s, 16, 64);
        if (tx == 0) {
            if (o < DIM_G) u[b * DIM_G + o] = s;
            else           v[b * DIM_Z + (o - DIM_G)] = s;
        }
    }
}

// -- kernel 2: W[b,g,d] = W_base + u*v -> bf16 (+ transposed WT), b = h&7 --
// XCD-aligned so each batch's W/WT land dirty in the L2 of the XCD whose GEMM
// blocks (same b = xcd mapping) will read them.
__global__ void wpack_kernel(const float* __restrict__ Wbase,
                             const float* __restrict__ u, const float* __restrict__ v,
                             u16* __restrict__ W, u16* __restrict__ WT) {
    __shared__ u16 tile[32][33];
    int h = blockIdx.x;
    int b = h & 7, t8 = h >> 3;          // t8 in [0,512)
    int d0 = (t8 & 15) * 32, g0 = (t8 >> 4) * 32;
    int tx = threadIdx.x, ty = threadIdx.y;
    float vb = v[b * DIM_Z + d0 + tx];
#pragma unroll
    for (int j = 0; j < 4; ++j) {
        int g = g0 + ty + j * 8;
        u16 h16 = f2b(Wbase[(size_t)g * DIM_Z + d0 + tx] + u[b * DIM_G + g] * vb);
        W[((size_t)b * DIM_G + g) * DIM_Z + d0 + tx] = h16;
        tile[ty + j * 8][tx] = h16;
    }
    __syncthreads();
#pragma unroll
    for (int j = 0; j < 4; ++j)
        WT[((size_t)b * DIM_Z + d0 + ty + j * 8) * DIM_G + g0 + tx] =
            tile[tx][ty + j * 8];
}

// ---------------- GEMM1: qg = relu(qz @ W[b]^T); rsum[m] = row-sum ----------------
// A = qz f32 DIRECT (fused cast: reg-stage f32 issue-early, cvt, swizzled
// ds_write — r4/r6-verified). B = W[b] via global_load_lds (linear dest, source
// chunk pre-swizzled cw = c'^(row&7); reads same XOR — rule #21, 0 conflicts).
// 128x128 tile, 4 waves (2x2), BK=64, (256,4).
// XCD decode: xcd = h&7 owns batch xcd's m-range; n-fastest within (A-panel
// sharing). qg stored NORMAL (must stay L2-hot for GEMM2 — r9-vs-r13 lesson).
__global__ __launch_bounds__(256, 4)
void gemm1(const float* __restrict__ qz, const u16* __restrict__ Wall,
           u16* __restrict__ qg, float* __restrict__ rsum) {
    const int N = DIM_G, K = DIM_Z;
    __shared__ u16 As[128 * BK];   // 16 KB
    __shared__ u16 Bs[128 * BK];   // 16 KB

    int h = blockIdx.x;
    int xcd = h & 7, idx = h >> 3;
    int tile = xcd * 128 + idx;              // 16 mT x 8 nT per XCD
    int mBase = (tile >> 3) * 128;
    int nBase = (tile & 7) * 128;
    int b = mBase >> 11;                      // == xcd

    int tid  = threadIdx.x;
    int lane = tid & 63, wid = tid >> 6;
    int wm = wid >> 1, wn = wid & 1;
    int lr = lane & 15, lg = lane >> 4;

    f32x4 acc[4][4] = {};

    int sRow = tid >> 3;                      // 0..31
    int sC   = tid & 7;
    int cw   = sC ^ (sRow & 7);
    const float* aSrc = qz + (size_t)(mBase + sRow) * K + sC * 8;     // straight
    const u16*   bSrc = Wall + (size_t)b * DIM_G * DIM_Z
                             + (size_t)(nBase + sRow) * K + cw * 8;   // pre-swz

    for (int kt = 0; kt < K; kt += BK) {
        float4 alo[4], ahi[4];
#pragma unroll
        for (int r = 0; r < 4; ++r) {         // issue-early: no LDS hazard
            const float* g = aSrc + (size_t)r * 32 * K + kt;
            alo[r] = *(const float4*)g;
            ahi[r] = *(const float4*)(g + 4);
        }
        __syncthreads();   // previous tile's reads done before overwrite
#pragma unroll
        for (int r = 0; r < 4; ++r)
            GLD16(bSrc + (size_t)r * 32 * K + kt, &Bs[(r * 256 + wid * 64) * 8]);
#pragma unroll
        for (int r = 0; r < 4; ++r) {         // cvt + swizzled ds_write
            union { u16 us[8]; uint4 q; } o;
            o.us[0] = f2b(alo[r].x); o.us[1] = f2b(alo[r].y);
            o.us[2] = f2b(alo[r].z); o.us[3] = f2b(alo[r].w);
            o.us[4] = f2b(ahi[r].x); o.us[5] = f2b(ahi[r].y);
            o.us[6] = f2b(ahi[r].z); o.us[7] = f2b(ahi[r].w);
            *(uint4*)&As[(r * 32 + sRow) * BK + cw * 8] = o.q;
        }
        __syncthreads();   // tile landed
#pragma unroll
        for (int ks = 0; ks < 2; ++ks) {
            bf16x8 af[4], bfr[4];
#pragma unroll
            for (int mi = 0; mi < 4; ++mi) {
                int row = wm * 64 + mi * 16 + lr;
                int cq  = (ks * 4 + lg) ^ (row & 7);
                af[mi] = *(const bf16x8*)&As[row * BK + cq * 8];
            }
#pragma unroll
            for (int ni = 0; ni < 4; ++ni) {
                int row = wn * 64 + ni * 16 + lr;
                int cq  = (ks * 4 + lg) ^ (row & 7);
                bfr[ni] = *(const bf16x8*)&Bs[row * BK + cq * 8];
            }
            __builtin_amdgcn_s_setprio(1);
#pragma unroll
            for (int mi = 0; mi < 4; ++mi)
#pragma unroll
                for (int ni = 0; ni < 4; ++ni)
                    acc[mi][ni] = __builtin_amdgcn_mfma_f32_16x16x32_bf16(
                        af[mi], bfr[ni], acc[mi][ni], 0, 0, 0);
            __builtin_amdgcn_s_setprio(0);
        }
    }

    int mw = mBase + wm * 64, nw = nBase + wn * 64;
#pragma unroll
    for (int mi = 0; mi < 4; ++mi)
#pragma unroll
        for (int r = 0; r < 4; ++r) {
            int m = mw + mi * 16 + lg * 4 + r;
            float vals[4];
            float s = 0.f;
#pragma unroll
            for (int ni = 0; ni < 4; ++ni) {
                vals[ni] = fmaxf(acc[mi][ni][r], 0.f);
                s += vals[ni];
            }
#pragma unroll
            for (int ni = 0; ni < 4; ++ni)
                qg[(size_t)m * N + nw + ni * 16 + lr] = f2b(vals[ni]);
            s += __shfl_xor(s, 1, 64);
            s += __shfl_xor(s, 2, 64);
            s += __shfl_xor(s, 4, 64);
            s += __shfl_xor(s, 8, 64);
            if (lr == 0) atomicAdd(&rsum[m], s);
        }
}

// ---------------- GEMM2: out = (qg @ WT[b]^T) / max(rsum,eps) ----------------
// The r13-proven ~24 µs structure: both operands via global_load_lds, (256,4),
// same per-XCD m-range as GEMM1 (qg L2-hot), NT store (out never re-read).
__global__ __launch_bounds__(256, 4)
void gemm2(const u16* __restrict__ qg, const u16* __restrict__ WTall,
           const float* __restrict__ rsum, float* __restrict__ out) {
    const int N = DIM_Z, K = DIM_G;
    __shared__ u16 As[128 * BK];   // 16 KB
    __shared__ u16 Bs[128 * BK];   // 16 KB

    int h = blockIdx.x;
    int xcd = h & 7, idx = h >> 3;
    int tile = xcd * 64 + idx;               // 16 mT x 4 nT per XCD
    int mBase = (tile >> 2) * 128;
    int nBase = (tile & 3) * 128;
    int b = mBase >> 11;                      // == xcd

    int tid  = threadIdx.x;
    int lane = tid & 63, wid = tid >> 6;
    int wm = wid >> 1, wn = wid & 1;
    int lr = lane & 15, lg = lane >> 4;

    f32x4 acc[4][4] = {};

    int sRow = tid >> 3;
    int cw   = (tid & 7) ^ (sRow & 7);
    const u16* aSrc = qg + (size_t)(mBase + sRow) * K + cw * 8;
    const u16* bSrc = WTall + (size_t)b * DIM_Z * DIM_G
                            + (size_t)(nBase + sRow) * K + cw * 8;

    for (int kt = 0; kt < K; kt += BK) {
        __syncthreads();
#pragma unroll
        for (int r = 0; r < 4; ++r) {
            GLD16(aSrc + (size_t)r * 32 * K + kt, &As[(r * 256 + wid * 64) * 8]);
            GLD16(bSrc + (size_t)r * 32 * K + kt, &Bs[(r * 256 + wid * 64) * 8]);
        }
        __syncthreads();
#pragma unroll
        for (int ks = 0; ks < 2; ++ks) {
            bf16x8 af[4], bfr[4];
#pragma unroll
            for (int mi = 0; mi < 4; ++mi) {
                int row = wm * 64 + mi * 16 + lr;
                int cq  = (ks * 4 + lg) ^ (row & 7);
                af[mi] = *(const bf16x8*)&As[row * BK + cq * 8];
            }
#pragma unroll
            for (int ni = 0; ni < 4; ++ni) {
                int row = wn * 64 + ni * 16 + lr;
                int cq  = (ks * 4 + lg) ^ (row & 7);
                bfr[ni] = *(const bf16x8*)&Bs[row * BK + cq * 8];
            }
            __builtin_amdgcn_s_setprio(1);
#pragma unroll
            for (int mi = 0; mi < 4; ++mi)
#pragma unroll
                for (int ni = 0; ni < 4; ++ni)
                    acc[mi][ni] = __builtin_amdgcn_mfma_f32_16x16x32_bf16(
                        af[mi], bfr[ni], acc[mi][ni], 0, 0, 0);
            __builtin_amdgcn_s_setprio(0);
        }
    }

    int mw = mBase + wm * 64, nw = nBase + wn * 64;
#pragma unroll
    for (int mi = 0; mi < 4; ++mi)
#pragma unroll
        for (int r = 0; r < 4; ++r) {
            int m = mw + mi * 16 + lg * 4 + r;
            float inv = 1.f / fmaxf(rsum[m], EPS);
#pragma unroll
            for (int ni = 0; ni < 4; ++ni)
                __builtin_nontemporal_store(acc[mi][ni][r] * inv,
                    &out[(size_t)m * N + nw + ni * 16 + lr]);
        }
}

extern "C" void kernel_launch(void* const* d_in, const int* in_sizes, int n_in,
                              void* d_out, int out_size, void* d_ws, size_t ws_size,
                              hipStream_t stream) {
    const float* qz    = (const float*)d_in[0];
    const int*   attr  = (const int*)d_in[1];
    const float* Wbase = (const float*)d_in[2];
    const float* emb   = (const float*)d_in[3];
    const float* Wu    = (const float*)d_in[4];
    const float* Wv    = (const float*)d_in[5];
    float* out = (float*)d_out;

    // workspace carve-up (all 256B aligned)
    char* ws = (char*)d_ws;
    size_t off = 0;
    auto alloc = [&](size_t bytes) -> void* {
        void* p = ws + off;
        off = (off + bytes + 255) & ~(size_t)255;
        return p;
    };
    float* u    = (float*)alloc((size_t)BATCH * DIM_G * 4);
    float* v    = (float*)alloc((size_t)BATCH * DIM_Z * 4);
    float* rsum = (float*)alloc((size_t)MTOT * 4);
    u16*   W    = (u16*)  alloc((size_t)BATCH * DIM_G * DIM_Z * 2);
    u16*   WT   = (u16*)  alloc((size_t)BATCH * DIM_G * DIM_Z * 2);
    u16*   qg   = (u16*)  alloc((size_t)MTOT * DIM_G * 2);
    if (off > ws_size) return;  // fail loudly (zero output) rather than corrupt

    uv_kernel<<<dim3(6, BATCH), dim3(256), 0, stream>>>(emb, attr, Wu, Wv, u, v, rsum);

    wpack_kernel<<<dim3(4096), dim3(32, 8), 0, stream>>>(Wbase, u, v, W, WT);

    // GEMM1: 16 mT x 8 nT x 8 xcd = 1024 blocks (fused f32-A cast)
    gemm1<<<dim3(1024), dim3(256), 0, stream>>>(qz, W, qg, rsum);

    // GEMM2: 16 mT x 4 nT x 8 xcd = 512 blocks (r13-proven ~24 µs shape)
    gemm2<<<dim3(512), dim3(256), 0, stream>>>(qg, WT, rsum, out);
}

// Round 15
// 84.730 us; speedup vs baseline: 1.1963x; 1.0023x over previous
//
#include <hip/hip_runtime.h>
#include <hip/hip_bf16.h>

// Problem constants (from reference)
#define BATCH   8
#define MROWS   2048      // C*P per batch
#define MTOT    16384     // BATCH*MROWS
#define DIM_Z   512
#define DIM_G   1024
#define EDIM    128
#define EPS     1e-6f
#define BK      64        // K-step

typedef unsigned short u16;
typedef unsigned int   u32;
typedef __attribute__((ext_vector_type(8))) short bf16x8;
typedef __attribute__((ext_vector_type(4))) float f32x4;

// f32 -> bf16 round-to-nearest-even (bit trick; inputs are finite)
__device__ __forceinline__ u16 f2b(float f) {
    u32 x = __float_as_uint(f);
    u32 r = x + 0x7fffu + ((x >> 16) & 1u);
    return (u16)(r >> 16);
}

// packed f32 pair -> 2x bf16 in one u32 (RNE), single VALU inst on gfx950
__device__ __forceinline__ u32 cvtpk(float lo, float hi) {
    u32 r;
    asm("v_cvt_pk_bf16_f32 %0, %1, %2" : "=v"(r) : "v"(lo), "v"(hi));
    return r;
}

// async global->LDS, 16B per lane, dest = wave-uniform base + lane*16
#define GLD16(gsrc, ldst) __builtin_amdgcn_global_load_lds( \
    (const __attribute__((address_space(1))) unsigned int*)(gsrc), \
    (__attribute__((address_space(3))) unsigned int*)(ldst), 16, 0, 0)

// ---- kernel 1: u = a_emb @ Wu^T, v = a_emb @ Wv^T (coalesced); zero rsum ----
__global__ void uv_kernel(const float* __restrict__ emb, const int* __restrict__ idx,
                          const float* __restrict__ Wu, const float* __restrict__ Wv,
                          float* __restrict__ u, float* __restrict__ v,
                          float* __restrict__ rsum) {
    __shared__ float a[EDIM];
    int b = blockIdx.y;
    int t = threadIdx.x;
    if (blockIdx.x == 0)   // zero rsum slice for batch b (runs before GEMM1)
        for (int i = t; i < MROWS; i += 256) rsum[(size_t)b * MROWS + i] = 0.f;
    if (t < EDIM) a[t] = emb[(size_t)idx[b] * EDIM + t];
    __syncthreads();
    int tx = t & 31, ty = t >> 5;
    int oBase = blockIdx.x * 256;
    for (int o0 = 0; o0 < 256; o0 += 8) {
        int o = oBase + o0 + ty;
        const float* wrow = (o < DIM_G) ? (Wu + (size_t)o * EDIM)
                                        : (Wv + (size_t)(o - DIM_G) * EDIM);
        float s = 0.f;
#pragma unroll
        for (int q = 0; q < 4; ++q) s += a[q * 32 + tx] * wrow[q * 32 + tx];
        s += __shfl_xor(s, 1, 64);
        s += __shfl_xor(s, 2, 64);
        s += __shfl_xor(s, 4, 64);
        s += __shfl_xor(s, 8, 64);
        s += __shfl_xor(s, 16, 64);
        if (tx == 0) {
            if (o < DIM_G) u[b * DIM_G + o] = s;
            else           v[b * DIM_Z + (o - DIM_G)] = s;
        }
    }
}

// -- kernel 2: W[b,g,d] = W_base + u*v -> bf16 (+ transposed WT), b = h&7 --
// XCD-aligned so each batch's W/WT land dirty in the L2 of the XCD whose GEMM
// blocks (same b = xcd mapping) will read them.
__global__ void wpack_kernel(const float* __restrict__ Wbase,
                             const float* __restrict__ u, const float* __restrict__ v,
                             u16* __restrict__ W, u16* __restrict__ WT) {
    __shared__ u16 tile[32][33];
    int h = blockIdx.x;
    int b = h & 7, t8 = h >> 3;          // t8 in [0,512)
    int d0 = (t8 & 15) * 32, g0 = (t8 >> 4) * 32;
    int tx = threadIdx.x, ty = threadIdx.y;
    float vb = v[b * DIM_Z + d0 + tx];
#pragma unroll
    for (int j = 0; j < 4; ++j) {
        int g = g0 + ty + j * 8;
        u16 h16 = f2b(Wbase[(size_t)g * DIM_Z + d0 + tx] + u[b * DIM_G + g] * vb);
        W[((size_t)b * DIM_G + g) * DIM_Z + d0 + tx] = h16;
        tile[ty + j * 8][tx] = h16;
    }
    __syncthreads();
#pragma unroll
    for (int j = 0; j < 4; ++j)
        WT[((size_t)b * DIM_Z + d0 + ty + j * 8) * DIM_G + g0 + tx] =
            tile[tx][ty + j * 8];
}

// ---------------- GEMM1: qg = relu(qz @ W[b]^T); rsum[m] = row-sum ----------------
// A = qz f32 DIRECT with PACKED convert (v_cvt_pk_bf16_f32: 16 insts/iter vs
// ~128 for scalar f2b — r14 diagnosis: gemm1 was VALU-bound on the cvt chain).
// B = W[b] via global_load_lds (linear dest, source chunk pre-swizzled
// cw = c'^(row&7); reads same XOR — rule #21, 0 conflicts measured).
// 128x128 tile, 4 waves (2x2), BK=64, (256,4).
// XCD decode: xcd = h&7 owns batch xcd's m-range; n-fastest within (A-panel
// sharing). qg stored NORMAL (must stay L2-hot for GEMM2 — r9-vs-r13 lesson).
__global__ __launch_bounds__(256, 4)
void gemm1(const float* __restrict__ qz, const u16* __restrict__ Wall,
           u16* __restrict__ qg, float* __restrict__ rsum) {
    const int N = DIM_G, K = DIM_Z;
    __shared__ u16 As[128 * BK];   // 16 KB
    __shared__ u16 Bs[128 * BK];   // 16 KB

    int h = blockIdx.x;
    int xcd = h & 7, idx = h >> 3;
    int tile = xcd * 128 + idx;              // 16 mT x 8 nT per XCD
    int mBase = (tile >> 3) * 128;
    int nBase = (tile & 7) * 128;
    int b = mBase >> 11;                      // == xcd

    int tid  = threadIdx.x;
    int lane = tid & 63, wid = tid >> 6;
    int wm = wid >> 1, wn = wid & 1;
    int lr = lane & 15, lg = lane >> 4;

    f32x4 acc[4][4] = {};

    int sRow = tid >> 3;                      // 0..31
    int sC   = tid & 7;
    int cw   = sC ^ (sRow & 7);
    const float* aSrc = qz + (size_t)(mBase + sRow) * K + sC * 8;     // straight
    const u16*   bSrc = Wall + (size_t)b * DIM_G * DIM_Z
                             + (size_t)(nBase + sRow) * K + cw * 8;   // pre-swz

    for (int kt = 0; kt < K; kt += BK) {
        float4 alo[4], ahi[4];
#pragma unroll
        for (int r = 0; r < 4; ++r) {         // issue-early: no LDS hazard
            const float* g = aSrc + (size_t)r * 32 * K + kt;
            alo[r] = *(const float4*)g;
            ahi[r] = *(const float4*)(g + 4);
        }
        __syncthreads();   // previous tile's reads done before overwrite
#pragma unroll
        for (int r = 0; r < 4; ++r)
            GLD16(bSrc + (size_t)r * 32 * K + kt, &Bs[(r * 256 + wid * 64) * 8]);
#pragma unroll
        for (int r = 0; r < 4; ++r) {         // packed cvt + swizzled ds_write
            uint4 q;
            q.x = cvtpk(alo[r].x, alo[r].y);
            q.y = cvtpk(alo[r].z, alo[r].w);
            q.z = cvtpk(ahi[r].x, ahi[r].y);
            q.w = cvtpk(ahi[r].z, ahi[r].w);
            *(uint4*)&As[(r * 32 + sRow) * BK + cw * 8] = q;
        }
        __syncthreads();   // tile landed
#pragma unroll
        for (int ks = 0; ks < 2; ++ks) {
            bf16x8 af[4], bfr[4];
#pragma unroll
            for (int mi = 0; mi < 4; ++mi) {
                int row = wm * 64 + mi * 16 + lr;
                int cq  = (ks * 4 + lg) ^ (row & 7);
                af[mi] = *(const bf16x8*)&As[row * BK + cq * 8];
            }
#pragma unroll
            for (int ni = 0; ni < 4; ++ni) {
                int row = wn * 64 + ni * 16 + lr;
                int cq  = (ks * 4 + lg) ^ (row & 7);
                bfr[ni] = *(const bf16x8*)&Bs[row * BK + cq * 8];
            }
            __builtin_amdgcn_s_setprio(1);
#pragma unroll
            for (int mi = 0; mi < 4; ++mi)
#pragma unroll
                for (int ni = 0; ni < 4; ++ni)
                    acc[mi][ni] = __builtin_amdgcn_mfma_f32_16x16x32_bf16(
                        af[mi], bfr[ni], acc[mi][ni], 0, 0, 0);
            __builtin_amdgcn_s_setprio(0);
        }
    }

    int mw = mBase + wm * 64, nw = nBase + wn * 64;
#pragma unroll
    for (int mi = 0; mi < 4; ++mi)
#pragma unroll
        for (int r = 0; r < 4; ++r) {
            int m = mw + mi * 16 + lg * 4 + r;
            float vals[4];
            float s = 0.f;
#pragma unroll
            for (int ni = 0; ni < 4; ++ni) {
                vals[ni] = fmaxf(acc[mi][ni][r], 0.f);
                s += vals[ni];
            }
#pragma unroll
            for (int ni = 0; ni < 4; ++ni)
                qg[(size_t)m * N + nw + ni * 16 + lr] = f2b(vals[ni]);
            s += __shfl_xor(s, 1, 64);
            s += __shfl_xor(s, 2, 64);
            s += __shfl_xor(s, 4, 64);
            s += __shfl_xor(s, 8, 64);
            if (lr == 0) atomicAdd(&rsum[m], s);
        }
}

// ---------------- GEMM2: out = (qg @ WT[b]^T) / max(rsum,eps) ----------------
// The r13-proven ~24 µs structure: both operands via global_load_lds, (256,4),
// same per-XCD m-range as GEMM1 (qg L2-hot), NT store (out never re-read).
__global__ __launch_bounds__(256, 4)
void gemm2(const u16* __restrict__ qg, const u16* __restrict__ WTall,
           const float* __restrict__ rsum, float* __restrict__ out) {
    const int N = DIM_Z, K = DIM_G;
    __shared__ u16 As[128 * BK];   // 16 KB
    __shared__ u16 Bs[128 * BK];   // 16 KB

    int h = blockIdx.x;
    int xcd = h & 7, idx = h >> 3;
    int tile = xcd * 64 + idx;               // 16 mT x 4 nT per XCD
    int mBase = (tile >> 2) * 128;
    int nBase = (tile & 3) * 128;
    int b = mBase >> 11;                      // == xcd

    int tid  = threadIdx.x;
    int lane = tid & 63, wid = tid >> 6;
    int wm = wid >> 1, wn = wid & 1;
    int lr = lane & 15, lg = lane >> 4;

    f32x4 acc[4][4] = {};

    int sRow = tid >> 3;
    int cw   = (tid & 7) ^ (sRow & 7);
    const u16* aSrc = qg + (size_t)(mBase + sRow) * K + cw * 8;
    const u16* bSrc = WTall + (size_t)b * DIM_Z * DIM_G
                            + (size_t)(nBase + sRow) * K + cw * 8;

    for (int kt = 0; kt < K; kt += BK) {
        __syncthreads();
#pragma unroll
        for (int r = 0; r < 4; ++r) {
            GLD16(aSrc + (size_t)r * 32 * K + kt, &As[(r * 256 + wid * 64) * 8]);
            GLD16(bSrc + (size_t)r * 32 * K + kt, &Bs[(r * 256 + wid * 64) * 8]);
        }
        __syncthreads();
#pragma unroll
        for (int ks = 0; ks < 2; ++ks) {
            bf16x8 af[4], bfr[4];
#pragma unroll
            for (int mi = 0; mi < 4; ++mi) {
                int row = wm * 64 + mi * 16 + lr;
                int cq  = (ks * 4 + lg) ^ (row & 7);
                af[mi] = *(const bf16x8*)&As[row * BK + cq * 8];
            }
#pragma unroll
            for (int ni = 0; ni < 4; ++ni) {
                int row = wn * 64 + ni * 16 + lr;
                int cq  = (ks * 4 + lg) ^ (row & 7);
                bfr[ni] = *(const bf16x8*)&Bs[row * BK + cq * 8];
            }
            __builtin_amdgcn_s_setprio(1);
#pragma unroll
            for (int mi = 0; mi < 4; ++mi)
#pragma unroll
                for (int ni = 0; ni < 4; ++ni)
                    acc[mi][ni] = __builtin_amdgcn_mfma_f32_16x16x32_bf16(
                        af[mi], bfr[ni], acc[mi][ni], 0, 0, 0);
            __builtin_amdgcn_s_setprio(0);
        }
    }

    int mw = mBase + wm * 64, nw = nBase + wn * 64;
#pragma unroll
    for (int mi = 0; mi < 4; ++mi)
#pragma unroll
        for (int r = 0; r < 4; ++r) {
            int m = mw + mi * 16 + lg * 4 + r;
            float inv = 1.f / fmaxf(rsum[m], EPS);
#pragma unroll
            for (int ni = 0; ni < 4; ++ni)
                __builtin_nontemporal_store(acc[mi][ni][r] * inv,
                    &out[(size_t)m * N + nw + ni * 16 + lr]);
        }
}

extern "C" void kernel_launch(void* const* d_in, const int* in_sizes, int n_in,
                              void* d_out, int out_size, void* d_ws, size_t ws_size,
                              hipStream_t stream) {
    const float* qz    = (const float*)d_in[0];
    const int*   attr  = (const int*)d_in[1];
    const float* Wbase = (const float*)d_in[2];
    const float* emb   = (const float*)d_in[3];
    const float* Wu    = (const float*)d_in[4];
    const float* Wv    = (const float*)d_in[5];
    float* out = (float*)d_out;

    // workspace carve-up (all 256B aligned)
    char* ws = (char*)d_ws;
    size_t off = 0;
    auto alloc = [&](size_t bytes) -> void* {
        void* p = ws + off;
        off = (off + bytes + 255) & ~(size_t)255;
        return p;
    };
    float* u    = (float*)alloc((size_t)BATCH * DIM_G * 4);
    float* v    = (float*)alloc((size_t)BATCH * DIM_Z * 4);
    float* rsum = (float*)alloc((size_t)MTOT * 4);
    u16*   W    = (u16*)  alloc((size_t)BATCH * DIM_G * DIM_Z * 2);
    u16*   WT   = (u16*)  alloc((size_t)BATCH * DIM_G * DIM_Z * 2);
    u16*   qg   = (u16*)  alloc((size_t)MTOT * DIM_G * 2);
    if (off > ws_size) return;  // fail loudly (zero output) rather than corrupt

    uv_kernel<<<dim3(6, BATCH), dim3(256), 0, stream>>>(emb, attr, Wu, Wv, u, v, rsum);

    wpack_kernel<<<dim3(4096), dim3(32, 8), 0, stream>>>(Wbase, u, v, W, WT);

    // GEMM1: 16 mT x 8 nT x 8 xcd = 1024 blocks (fused f32-A cast, packed cvt)
    gemm1<<<dim3(1024), dim3(256), 0, stream>>>(qz, W, qg, rsum);

    // GEMM2: 16 mT x 4 nT x 8 xcd = 512 blocks (r13-proven ~24 µs shape)
    gemm2<<<dim3(512), dim3(256), 0, stream>>>(qg, WT, rsum, out);
}